// Round 4
// baseline (132.615 us; speedup 1.0000x reference)
//
#include <hip/hip_runtime.h>
#include <hip/hip_bf16.h>
#include <stdint.h>

#define T_DIM 256
#define B_DIM 128
#define I_DIM 512
#define H_DIM 1024
#define M_DIM (T_DIM * B_DIM)

typedef __attribute__((ext_vector_type(4))) float f32x4;
typedef __attribute__((ext_vector_type(8))) short short8;  // 8 bf16 in 4 VGPRs

__device__ inline unsigned short f2bf(float f) {
    __hip_bfloat16 h = __float2bfloat16(f);  // RNE
    unsigned short u;
    __builtin_memcpy(&u, &h, sizeof(u));
    return u;
}

// async 16B global -> LDS (direct). LDS dest is wave-uniform base + lane*16
// (lane-linear); any swizzle must be baked into the GLOBAL source layout.
__device__ inline void gload_lds16(const void* g, void* l) {
    __builtin_amdgcn_global_load_lds(
        (const __attribute__((address_space(1))) uint32_t*)g,
        (__attribute__((address_space(3))) uint32_t*)l, 16, 0, 0);
}

// ---------------------------------------------------------------------------
// pack_swz: f32 (rows x 512) -> bf16 swizzled LDS image, 16B granules.
// Image granule ((tile*8 + kst)*1024 + row*8 + slot) = src cols
// kst*64 + (slot^(row&7))*8 .. +8 of src row tile*128+row. The GEMM stages
// this linearly with gload_lds and reads granule g of row r at slot g^(r&7)
// (conflict-free ds_read_b128, <=2-way). Used for both x (tiles=256) and
// W_ih (tiles=8); row stride is I_DIM=512 f32 for both.
// ---------------------------------------------------------------------------
__global__ void pack_swz(const float* __restrict__ src,
                         unsigned short* __restrict__ dst) {
    int id = blockIdx.x * 256 + threadIdx.x;
    int slot = id & 7;
    int row = (id >> 3) & 127;
    int kst = (id >> 10) & 7;
    int tile = id >> 13;
    int g = slot ^ (row & 7);
    const float* s = src + (size_t)(tile * 128 + row) * I_DIM + kst * 64 + g * 8;
    f32x4 lo = *(const f32x4*)s;
    f32x4 hi = *(const f32x4*)(s + 4);
    union { unsigned short us[8]; short8 v; } pk;
#pragma unroll
    for (int j = 0; j < 4; ++j) { pk.us[j] = f2bf(lo[j]); pk.us[4 + j] = f2bf(hi[j]); }
    *(short8*)(dst + (size_t)id * 8) = pk.v;
}

// ---------------------------------------------------------------------------
// Main GEMM: out[m][h] = relu(Xp[m].Wp[h] + biasall[m&127][h]).
// 128x128 tile, BK=64, 4 waves (2x2), 16x16x32 bf16 MFMA.
// Double-buffered LDS (64 KB -> 2 blocks/CU) + counted s_waitcnt vmcnt(8):
// tile k+1's 8 gload_lds stay in flight across the barrier while tile k
// computes; vmcnt never drains to 0 in the main loop (T3/T4 minimum-2-phase).
// ---------------------------------------------------------------------------
__global__ __launch_bounds__(256, 2) void gemm_main(
    const unsigned short* __restrict__ Xp, const unsigned short* __restrict__ Wp,
    const float* __restrict__ biasall, float* __restrict__ C,
    float* __restrict__ Clast) {
    __shared__ unsigned short As[2][128 * 64];  // 16 KB each
    __shared__ unsigned short Bs[2][128 * 64];

    const int tid = threadIdx.x;
    const int lane = tid & 63;
    const int wid = tid >> 6;
    const int wr = wid >> 1, wc = wid & 1;
    const int llo = lane & 15, lhi = lane >> 4;

    // XCD-aware swizzle (grid = 2048, divisible by 8)
    const int orig = blockIdx.x;
    const int wg = ((orig & 7) * (2048 >> 3)) + (orig >> 3);
    const int mt = wg >> 3;
    const int nt = wg & 7;
    const int m0 = mt * 128;
    const int n0 = nt * 128;

    const unsigned short* Abase = Xp + (size_t)mt * 65536 + (size_t)tid * 8;
    const unsigned short* Bbase = Wp + (size_t)nt * 65536 + (size_t)tid * 8;

    auto stage = [&](int kst, int buf) {
        const unsigned short* a = Abase + (size_t)kst * 8192;
        const unsigned short* b = Bbase + (size_t)kst * 8192;
#pragma unroll
        for (int g = 0; g < 4; ++g)
            gload_lds16(a + g * 2048, (char*)As[buf] + (g * 256 + tid) * 16);
#pragma unroll
        for (int g = 0; g < 4; ++g)
            gload_lds16(b + g * 2048, (char*)Bs[buf] + (g * 256 + tid) * 16);
    };

    f32x4 acc[4][4] = {};

    auto compute = [&](int buf) {
#pragma unroll
        for (int ks = 0; ks < 2; ++ks) {
            short8 af[4], bfv[4];
#pragma unroll
            for (int mi = 0; mi < 4; ++mi) {
                int ar = wr * 64 + mi * 16 + llo;
                int g = ks * 4 + lhi;
                af[mi] = *(const short8*)&As[buf][ar * 64 + ((g ^ (ar & 7)) << 3)];
            }
#pragma unroll
            for (int ni = 0; ni < 4; ++ni) {
                int br = wc * 64 + ni * 16 + llo;
                int g = ks * 4 + lhi;
                bfv[ni] = *(const short8*)&Bs[buf][br * 64 + ((g ^ (br & 7)) << 3)];
            }
#pragma unroll
            for (int mi = 0; mi < 4; ++mi)
#pragma unroll
                for (int ni = 0; ni < 4; ++ni)
                    acc[mi][ni] = __builtin_amdgcn_mfma_f32_16x16x32_bf16(
                        af[mi], bfv[ni], acc[mi][ni], 0, 0, 0);
        }
    };

    stage(0, 0);   // 8 loads in flight
    stage(1, 1);   // 16 in flight
#pragma unroll
    for (int k = 0; k < 8; ++k) {
        // wait for tile k's 8 loads; keep tile k+1's (and later) in flight
        if (k < 7)
            asm volatile("s_waitcnt vmcnt(8)" ::: "memory");
        else
            asm volatile("s_waitcnt vmcnt(0)" ::: "memory");
        __builtin_amdgcn_s_barrier();        // all waves' tile-k stores landed
        __builtin_amdgcn_sched_barrier(0);   // pin: no ds_read hoisted above
        compute(k & 1);
        __builtin_amdgcn_sched_barrier(0);
        __builtin_amdgcn_s_barrier();        // all waves done reading buf k&1
        if (k + 2 < 8) stage(k + 2, k & 1);  // prefetch into freed buffer
    }

    // epilogue: bias + relu + store (+ out_last copy on final m-tile)
    const bool last_tile = (m0 == M_DIM - 128);
#pragma unroll
    for (int mi = 0; mi < 4; ++mi) {
#pragma unroll
        for (int ni = 0; ni < 4; ++ni) {
            int col = n0 + wc * 64 + ni * 16 + llo;
            int rowb = m0 + wr * 64 + mi * 16 + lhi * 4;
#pragma unroll
            for (int r = 0; r < 4; ++r) {
                int row = rowb + r;
                float v = acc[mi][ni][r] + biasall[(row & 127) * H_DIM + col];
                v = fmaxf(v, 0.0f);
                C[(size_t)row * H_DIM + col] = v;
                if (last_tile) Clast[(row & 127) * H_DIM + col] = v;
            }
        }
    }
}

// ---------------------------------------------------------------------------
// Reg-staged f32 kernel: MODE 0 builds biasall (tiny GEMM, 8 blocks);
// MODE 1 is the known-correct fallback main GEMM if ws is too small.
// ---------------------------------------------------------------------------
template <int MODE>
__global__ __launch_bounds__(256, 2) void gemm_bt(
    const float* __restrict__ A, const float* __restrict__ Bm,
    int M, int N, int K,
    const float* __restrict__ bias0, const float* __restrict__ bias1,
    float* __restrict__ C, float* __restrict__ Clast) {
    __shared__ unsigned short As[128 * 64];
    __shared__ unsigned short Bs[128 * 64];

    const int tid = threadIdx.x;
    const int wid = tid >> 6;
    const int lane = tid & 63;
    const int wr = wid >> 1, wc = wid & 1;
    const int lhi = lane >> 4;
    const int llo = lane & 15;

    const int orig = blockIdx.x;
    const int nwg = gridDim.x;
    const int wg = (nwg > 8 && (nwg & 7) == 0)
                       ? ((orig & 7) * (nwg >> 3) + (orig >> 3))
                       : orig;
    const int m0 = (wg >> 3) * 128;
    const int n0 = (wg & 7) * 128;

    const int srow = tid >> 3;
    const int c8 = tid & 7;
    const int slot8 = (c8 ^ (srow & 7)) * 8;

    const float* Aptr = A + (size_t)(m0 + srow) * K + c8 * 8;
    const float* Bptr = Bm + (size_t)(n0 + srow) * K + c8 * 8;

    f32x4 pf[2][4][2];

    auto issue = [&](int k0) {
#pragma unroll
        for (int g = 0; g < 4; ++g) {
            const float* pa = Aptr + (size_t)g * 32 * K + k0;
            const float* pb = Bptr + (size_t)g * 32 * K + k0;
            pf[0][g][0] = *(const f32x4*)pa;
            pf[0][g][1] = *(const f32x4*)(pa + 4);
            pf[1][g][0] = *(const f32x4*)pb;
            pf[1][g][1] = *(const f32x4*)(pb + 4);
        }
    };
    auto write_lds = [&]() {
#pragma unroll
        for (int g = 0; g < 4; ++g) {
            union { unsigned short s[8]; short8 v; } pka, pkb;
#pragma unroll
            for (int j = 0; j < 4; ++j) {
                pka.s[j] = f2bf(pf[0][g][0][j]);
                pka.s[4 + j] = f2bf(pf[0][g][1][j]);
                pkb.s[j] = f2bf(pf[1][g][0][j]);
                pkb.s[4 + j] = f2bf(pf[1][g][1][j]);
            }
            *(short8*)&As[(srow + g * 32) * 64 + slot8] = pka.v;
            *(short8*)&Bs[(srow + g * 32) * 64 + slot8] = pkb.v;
        }
    };

    f32x4 acc[4][4] = {};

    auto compute = [&]() {
#pragma unroll
        for (int ks = 0; ks < 2; ++ks) {
            short8 af[4], bfr[4];
#pragma unroll
            for (int mi = 0; mi < 4; ++mi) {
                int ar = wr * 64 + mi * 16 + llo;
                int slot = ((ks << 2) + lhi) ^ (ar & 7);
                af[mi] = *(const short8*)&As[ar * 64 + slot * 8];
            }
#pragma unroll
            for (int ni = 0; ni < 4; ++ni) {
                int br = wc * 64 + ni * 16 + llo;
                int slot = ((ks << 2) + lhi) ^ (br & 7);
                bfr[ni] = *(const short8*)&Bs[br * 64 + slot * 8];
            }
#pragma unroll
            for (int mi = 0; mi < 4; ++mi)
#pragma unroll
                for (int ni = 0; ni < 4; ++ni)
                    acc[mi][ni] = __builtin_amdgcn_mfma_f32_16x16x32_bf16(
                        af[mi], bfr[ni], acc[mi][ni], 0, 0, 0);
        }
    };

    issue(0);
    write_lds();
    __syncthreads();
    for (int k0 = 64; k0 < K; k0 += 64) {
        issue(k0);
        compute();
        __syncthreads();
        write_lds();
        __syncthreads();
    }
    compute();

    const bool last_tile = (m0 == M - 128);
#pragma unroll
    for (int mi = 0; mi < 4; ++mi) {
#pragma unroll
        for (int ni = 0; ni < 4; ++ni) {
            int col = n0 + wc * 64 + ni * 16 + llo;
            int rowb = m0 + wr * 64 + mi * 16 + lhi * 4;
            if (MODE == 0) {
                float bsum = bias0[col] + bias1[col];
#pragma unroll
                for (int r = 0; r < 4; ++r)
                    C[(size_t)(rowb + r) * N + col] = acc[mi][ni][r] + bsum;
            } else {
#pragma unroll
                for (int r = 0; r < 4; ++r) {
                    int row = rowb + r;
                    float v = acc[mi][ni][r] + bias0[(row & 127) * N + col];
                    v = fmaxf(v, 0.0f);
                    C[(size_t)row * N + col] = v;
                    if (last_tile) Clast[(row & 127) * N + col] = v;
                }
            }
        }
    }
}

extern "C" void kernel_launch(void* const* d_in, const int* in_sizes, int n_in,
                              void* d_out, int out_size, void* d_ws, size_t ws_size,
                              hipStream_t stream) {
    const float* x = (const float*)d_in[0];       // (T,B,I)
    const float* hidden = (const float*)d_in[1];  // (B,H)
    const float* W_ih = (const float*)d_in[2];    // (H,I)
    const float* W_hh = (const float*)d_in[3];    // (H,H)
    const float* b_ih = (const float*)d_in[4];    // (H,)
    const float* b_hh = (const float*)d_in[5];    // (H,)

    float* out = (float*)d_out;                              // (T,B,H)
    float* out_last = out + (size_t)T_DIM * B_DIM * H_DIM;   // (B,H)

    // ws layout: [0,512K) biasall f32 ; [512K,1.5M) Wp bf16 ; [1.5M,+32M) Xp bf16
    float* biasall = (float*)d_ws;
    unsigned short* Wp = (unsigned short*)((char*)d_ws + 512 * 1024);
    unsigned short* Xp = (unsigned short*)((char*)d_ws + 1536 * 1024);
    const size_t ws_need = 1536 * 1024 + (size_t)M_DIM * I_DIM * 2;

    // biasall[b][h] = hidden[b] . W_hh[h] + b_ih[h] + b_hh[h]
    gemm_bt<0><<<dim3(H_DIM / 128), dim3(256), 0, stream>>>(
        hidden, W_hh, B_DIM, H_DIM, H_DIM, b_ih, b_hh, biasall, nullptr);

    if (ws_size >= ws_need) {
        // pack x (256 tiles) and W_ih (8 tiles) into bf16 swizzled images
        pack_swz<<<dim3(M_DIM * I_DIM / 8 / 256), dim3(256), 0, stream>>>(x, Xp);
        pack_swz<<<dim3(H_DIM * I_DIM / 8 / 256), dim3(256), 0, stream>>>(W_ih, Wp);
        gemm_main<<<dim3(M_DIM / 128 * (H_DIM / 128)), dim3(256), 0, stream>>>(
            Xp, Wp, biasall, out, out_last);
    } else {
        gemm_bt<1><<<dim3(M_DIM / 128 * (H_DIM / 128)), dim3(256), 0, stream>>>(
            x, W_ih, M_DIM, H_DIM, I_DIM, biasall, nullptr, out, out_last);
    }
}